// Round 8
// baseline (1369.144 us; speedup 1.0000x reference)
//
#include <hip/hip_runtime.h>
#include <hip/hip_bf16.h>

#define N_NODES 10000
#define N_EDGES 70000
#define NPAD 10112   // 158*64
#define EPAD 70016   // 547*128
#define H 128
#define NLAYERS 15
constexpr float LN_EPS = 1e-5f;

typedef __attribute__((ext_vector_type(8))) short short8;
typedef __attribute__((ext_vector_type(4))) float f32x4;

__device__ __forceinline__ float bf2f(unsigned int ulo16) {
    return __uint_as_float(ulo16 << 16);
}
__device__ __forceinline__ unsigned short f2bf(float f) {
    unsigned int x = __float_as_uint(f);
    x += 0x7fffu + ((x >> 16) & 1u);
    return (unsigned short)(x >> 16);
}
__device__ __forceinline__ uint2 pack4(const f32x4& a) {
    uint2 u;
    u.x = (unsigned)f2bf(a[0]) | ((unsigned)f2bf(a[1]) << 16);
    u.y = (unsigned)f2bf(a[2]) | ((unsigned)f2bf(a[3]) << 16);
    return u;
}

// ---------------- prep kernels ----------------
__global__ void prep_node(const int* __restrict__ nt, const float* __restrict__ frames,
                          const float* __restrict__ nm, const float* __restrict__ ns,
                          unsigned short* __restrict__ a16b) {
    int i = blockIdx.x * blockDim.x + threadIdx.x;
    if (i >= NPAD * 32) return;
    int n = i >> 5, k = i & 31;
    float v = 0.f;
    if (n < N_NODES && k < 11) {
        float raw = (k < 2) ? frames[n * 2 + k] : ((nt[n] == (k - 2)) ? 1.f : 0.f);
        v = (raw - nm[k]) / ns[k];
    }
    a16b[i] = f2bf(v);
}

// edge features permuted into CSR (receiver-sorted) order
__global__ void prep_edge_sorted(const float* __restrict__ ef, const int* __restrict__ esorted,
                                 unsigned short* __restrict__ a4b) {
    int i = blockIdx.x * blockDim.x + threadIdx.x;
    if (i >= EPAD * 32) return;
    int p = i >> 5, k = i & 31;
    float v = 0.f;
    if (p < N_EDGES && k < 3) v = ef[(size_t)esorted[p] * 3 + k];
    a4b[i] = f2bf(v);
}

__global__ void permute_idx(const int* __restrict__ snd, const int* __restrict__ rcv,
                            const int* __restrict__ esorted,
                            int* __restrict__ sndP, int* __restrict__ rcvP) {
    int p = blockIdx.x * blockDim.x + threadIdx.x;
    if (p >= N_EDGES) return;
    int j = esorted[p];
    sndP[p] = snd[j];
    rcvP[p] = rcv[j];
}

// W[nmat][Kr][128] fp32 -> fragment-ordered bf16:
// fidx = (((m*(Kp/32) + (k>>5))*8 + (c>>4))*64 + ((k>>3)&3)*16 + (c&15))*8 + (k&7)
__global__ void transpose_w_frag(const float* __restrict__ w, unsigned short* __restrict__ wt,
                                 int Kr, int Kp, int nmat) {
    __shared__ float T[32][33];
    int nkt = Kp / 32;
    int bid = blockIdx.x;
    int m = bid / (nkt * 4);
    int rest = bid % (nkt * 4);
    int kt = rest / 4, ct = rest % 4;
    int t = threadIdx.x;
    int tc = t & 31, tr = t >> 5;  // tr 0..7
#pragma unroll
    for (int rr = 0; rr < 4; ++rr) {
        int k = kt * 32 + tr + rr * 8;
        int c = ct * 32 + tc;
        T[tr + rr * 8][tc] = (k < Kr) ? w[((size_t)m * Kr + k) * H + c] : 0.f;
    }
    __syncthreads();
#pragma unroll
    for (int rr = 0; rr < 4; ++rr) {
        int c = ct * 32 + tr + rr * 8;
        int k = kt * 32 + tc;
        size_t fidx = ((((size_t)m * nkt + (k >> 5)) * 8 + (c >> 4)) * 64
                       + ((k >> 3) & 3) * 16 + (c & 15)) * 8 + (k & 7);
        wt[fidx] = f2bf(T[tc][tr + rr * 8]);
    }
}

// ---------------- CSR build ----------------
__global__ void hist_kernel(const int* __restrict__ rcv, int* __restrict__ counts) {
    int j = blockIdx.x * blockDim.x + threadIdx.x;
    if (j < N_EDGES) atomicAdd(&counts[rcv[j]], 1);
}

__global__ void scan_kernel(const int* __restrict__ counts, int* __restrict__ starts) {
    __shared__ int part[1024];
    const int CH = 10;
    int t = threadIdx.x;
    int base = t * CH;
    int loc[CH];
    int s = 0;
#pragma unroll
    for (int i = 0; i < CH; i++) {
        int idx = base + i;
        int c = (idx < N_NODES) ? counts[idx] : 0;
        loc[i] = s;
        s += c;
    }
    part[t] = s;
    __syncthreads();
    for (int off = 1; off < 1024; off <<= 1) {
        int v = (t >= off) ? part[t - off] : 0;
        __syncthreads();
        part[t] += v;
        __syncthreads();
    }
    int pre = (t > 0) ? part[t - 1] : 0;
#pragma unroll
    for (int i = 0; i < CH; i++) {
        int idx = base + i;
        if (idx < N_NODES) starts[idx] = pre + loc[i];
    }
}

__global__ void scatter_kernel(const int* __restrict__ rcv, const int* __restrict__ starts,
                               int* __restrict__ cursor, int* __restrict__ esorted) {
    int j = blockIdx.x * blockDim.x + threadIdx.x;
    if (j >= N_EDGES) return;
    int r = rcv[j];
    int p = starts[r] + atomicAdd(&cursor[r], 1);
    esorted[p] = j;
}

// ---------------- segmented aggregation (contiguous after presort) ----------------
__global__ void agg_kernel(const unsigned short* __restrict__ enew,
                           const int* __restrict__ starts,
                           const int* __restrict__ counts,
                           unsigned short* __restrict__ aggb) {
    int n = blockIdx.x * 16 + (threadIdx.x >> 4);
    int l = threadIdx.x & 15;  // 8 cols each
    if (n >= N_NODES) return;
    float a[8];
#pragma unroll
    for (int q = 0; q < 8; ++q) a[q] = 0.f;
    int s0 = starts[n], cnt = counts[n];
    const unsigned short* base = enew + (size_t)s0 * H + l * 8;
    for (int j = 0; j < cnt; ++j) {
        uint4 v = *reinterpret_cast<const uint4*>(base + (size_t)j * H);
        a[0] += bf2f(v.x & 0xffffu); a[1] += bf2f(v.x >> 16);
        a[2] += bf2f(v.y & 0xffffu); a[3] += bf2f(v.y >> 16);
        a[4] += bf2f(v.z & 0xffffu); a[5] += bf2f(v.z >> 16);
        a[6] += bf2f(v.w & 0xffffu); a[7] += bf2f(v.w >> 16);
    }
    uint4 o;
    o.x = (unsigned int)f2bf(a[0]) | ((unsigned int)f2bf(a[1]) << 16);
    o.y = (unsigned int)f2bf(a[2]) | ((unsigned int)f2bf(a[3]) << 16);
    o.z = (unsigned int)f2bf(a[4]) | ((unsigned int)f2bf(a[5]) << 16);
    o.w = (unsigned int)f2bf(a[6]) | ((unsigned int)f2bf(a[7]) << 16);
    *reinterpret_cast<uint4*>(aggb + (size_t)n * H + l * 8) = o;
}

// ---------------- 2-phase pipelined fused MLP (block-shared B in LDS) ----------------
// Same pipeline as r7; epilogue restructured: LN outputs staged fp32 into the
// (now dead) wave-private Hw strip, read back row-linear, stored as float4/uint2
// fully coalesced. Numerics identical to r4-r7.
// AMODE: 0 plain A[rows][K1]; 1 edge concat(x[snd],x[rcv],e); 2 node concat(x,agg)
// EPI: 1 bias+LN -> out_fp, out_bf
//      2 bias+LN -> out_fp += o; out_bf = bf16(new)           (node residual)
//      3 bias+LN -> out_fp += o; out_bf = bf16(new); enew = bf16(o)
template <int K1, int AMODE, int EPI, int RW, int NW>
__launch_bounds__(NW * 64)
__global__ void mlp_pipe(const unsigned short* __restrict__ A,
                         const unsigned short* __restrict__ Xb,
                         const unsigned short* __restrict__ Eb,
                         const unsigned short* __restrict__ Gb,
                         const int* __restrict__ snd,
                         const int* __restrict__ rcv,
                         const unsigned short* __restrict__ Bt1,
                         const float* __restrict__ bias1,
                         const unsigned short* __restrict__ Bt2,
                         const float* __restrict__ bias2,
                         const float* __restrict__ lng,
                         const float* __restrict__ lnb,
                         unsigned short* __restrict__ out_bf,
                         float* __restrict__ out_fp,
                         unsigned short* __restrict__ enew_bf,
                         int nrows) {
    constexpr int NC1 = K1 / 32;
    constexpr int NC2 = 4;
    constexpr int NT = NC1 + NC2;
    constexpr int TH = NW * 64;
    constexpr int SLOADS = 8192 / (TH * 16);   // uint4 loads/thread per 8KB chunk
    constexpr int SH = H + 8;

    __shared__ __attribute__((aligned(16))) unsigned short Bs[2][4096];
    __shared__ __attribute__((aligned(16))) unsigned short Hs[NW * 16 * RW * SH];

    const int tid = threadIdx.x;
    const int wave = tid >> 6;
    const int lane = tid & 63;
    const int l15 = lane & 15;
    const int lhi = lane >> 4;
    const int wrow0 = (blockIdx.x * NW + wave) * (16 * RW);
    unsigned short* Hw = Hs + wave * (16 * RW) * SH;

    // per-lane A-source row pointers (A-frag row = wrow0 + i*16 + l15)
    const unsigned short* pS[RW];
    const unsigned short* pR[RW];
    const unsigned short* pE[RW];
#pragma unroll
    for (int i = 0; i < RW; ++i) {
        int grow = wrow0 + i * 16 + l15;
        if (AMODE == 0) {
            pS[i] = A + (size_t)grow * K1;
        } else if (AMODE == 1) {
            int e = (grow < nrows) ? grow : (nrows - 1);
            pS[i] = Xb + (size_t)snd[e] * H;
            pR[i] = Xb + (size_t)rcv[e] * H;
            pE[i] = Eb + (size_t)grow * H;
        } else {
            pS[i] = Xb + (size_t)grow * H;
            pR[i] = Gb + (size_t)grow * H;
        }
    }

    auto gatherA = [&](int t, short8* dst) {
#pragma unroll
        for (int i = 0; i < RW; ++i) {
            int kc = t * 32;
            const unsigned short* s;
            if (AMODE == 0)      s = pS[i] + kc;
            else if (AMODE == 1) s = (kc < H) ? pS[i] + kc
                                 : (kc < 2 * H) ? pR[i] + (kc - H)
                                 : pE[i] + (kc - 2 * H);
            else                 s = (kc < H) ? pS[i] + kc : pR[i] + (kc - H);
            dst[i] = *reinterpret_cast<const short8*>(s + lhi * 8);
        }
    };
    auto bsrc = [&](int t) -> const unsigned short* {
        return (t < NC1) ? Bt1 + (size_t)t * 4096 : Bt2 + (size_t)(t - NC1) * 4096;
    };

    // bias1 early (held in regs)
    float b1v[8];
#pragma unroll
    for (int j = 0; j < 8; ++j) b1v[j] = bias1[j * 16 + l15];

    // ---- prologue: stage chunk 0, gather A chunk 0 ----
    {
        const unsigned short* src = bsrc(0);
        uint4 st[SLOADS];
#pragma unroll
        for (int s2 = 0; s2 < SLOADS; ++s2)
            st[s2] = *reinterpret_cast<const uint4*>(src + (size_t)(s2 * TH + tid) * 8);
#pragma unroll
        for (int s2 = 0; s2 < SLOADS; ++s2)
            *reinterpret_cast<uint4*>(&Bs[0][(s2 * TH + tid) * 8]) = st[s2];
    }
    short8 af[RW];
    gatherA(0, af);
    __syncthreads();

    f32x4 acc[RW][8];
#pragma unroll
    for (int i = 0; i < RW; i++)
#pragma unroll
        for (int j = 0; j < 8; j++) acc[i][j] = (f32x4){0.f, 0.f, 0.f, 0.f};

    // ---- main pipelined loop over NT chunks ----
#pragma unroll
    for (int t = 0; t < NT; ++t) {
        const int cur = t & 1;
        // (a) issue next-chunk B loads + next A gather (latency hides under (b))
        uint4 stn[SLOADS];
        if (t + 1 < NT) {
            const unsigned short* src = bsrc(t + 1);
#pragma unroll
            for (int s2 = 0; s2 < SLOADS; ++s2)
                stn[s2] = *reinterpret_cast<const uint4*>(src + (size_t)(s2 * TH + tid) * 8);
        }
        short8 afn[RW];
        if (t + 1 < NC1) gatherA(t + 1, afn);

        // (b) compute chunk t
        short8 av[RW];
        if (t < NC1) {
#pragma unroll
            for (int i = 0; i < RW; ++i) av[i] = af[i];
        } else {
            const int c2 = t - NC1;
#pragma unroll
            for (int i = 0; i < RW; ++i)
                av[i] = *reinterpret_cast<const short8*>(
                    &Hw[(i * 16 + l15) * SH + c2 * 32 + lhi * 8]);
        }
#pragma unroll
        for (int j = 0; j < 8; ++j) {
            short8 bfr = *reinterpret_cast<const short8*>(&Bs[cur][j * 512 + lane * 8]);
#pragma unroll
            for (int i = 0; i < RW; ++i)
                acc[i][j] = __builtin_amdgcn_mfma_f32_16x16x32_bf16(av[i], bfr, acc[i][j], 0, 0, 0);
        }

        // (c) stage transition: h = relu(acc+b1) -> wave-private Hw; reset acc
        if (t == NC1 - 1) {
#pragma unroll
            for (int i = 0; i < RW; ++i)
#pragma unroll
                for (int r = 0; r < 4; ++r) {
                    int rl = i * 16 + lhi * 4 + r;
#pragma unroll
                    for (int j = 0; j < 8; ++j) {
                        float v = acc[i][j][r] + b1v[j];
                        Hw[rl * SH + j * 16 + l15] = f2bf(v > 0.f ? v : 0.f);
                    }
                }
#pragma unroll
            for (int i = 0; i < RW; ++i)
#pragma unroll
                for (int j = 0; j < 8; ++j) acc[i][j] = (f32x4){0.f, 0.f, 0.f, 0.f};
        }

        // (d) write staged B to other buffer; advance
        if (t + 1 < NT) {
#pragma unroll
            for (int s2 = 0; s2 < SLOADS; ++s2)
                *reinterpret_cast<uint4*>(&Bs[cur ^ 1][(s2 * TH + tid) * 8]) = stn[s2];
            if (t + 1 < NC1) {
#pragma unroll
                for (int i = 0; i < RW; ++i) af[i] = afn[i];
            }
            __syncthreads();
        }
    }

    // ---- epilogue: bias2 + LN; coalesced stores via wave-private LDS restage ----
    float bv[8], gv[8], lv[8];
#pragma unroll
    for (int j = 0; j < 8; ++j) {
        bv[j] = bias2[j * 16 + l15];
        gv[j] = lng[j * 16 + l15];
        lv[j] = lnb[j * 16 + l15];
    }

    // Hw strip is dead after the last stage-2 ds_read (same-wave program order).
    // Reuse it as a [4][132] fp32 scratch: 2112 B <= RW*4352 B. Stride 132 makes
    // both the strided writes and the float4 readbacks bank-conflict-free.
    float* Epf = reinterpret_cast<float*>(Hw);

#pragma unroll
    for (int i = 0; i < RW; ++i) {
#pragma unroll
        for (int r = 0; r < 4; ++r) {
            float v[8];
            float s = 0.f, s2 = 0.f;
#pragma unroll
            for (int j = 0; j < 8; ++j) {
                v[j] = acc[i][j][r] + bv[j];
                s += v[j];
                s2 += v[j] * v[j];
            }
#pragma unroll
            for (int m = 1; m < 16; m <<= 1) {
                s += __shfl_xor(s, m);
                s2 += __shfl_xor(s2, m);
            }
            float mean = s * (1.f / 128.f);
            float var = s2 * (1.f / 128.f) - mean * mean;
            float rstd = rsqrtf(var + LN_EPS);
            // stage this (i,r) group's 4 rows (one per lhi) as fp32
#pragma unroll
            for (int j = 0; j < 8; ++j)
                Epf[lhi * 132 + j * 16 + l15] = (v[j] - mean) * rstd * gv[j] + lv[j];
            // read back row-linear, store coalesced (pad rows in-bounds by design)
#pragma unroll
            for (int q = 0; q < 2; ++q) {
                int lin = q * 64 + lane;
                int lrow = lin >> 5;     // 0..3 -> global row wrow0+i*16+lrow*4+r
                int c4 = lin & 31;       // float4 column index
                f32x4 o4 = *reinterpret_cast<const f32x4*>(&Epf[lrow * 132 + c4 * 4]);
                int grow = wrow0 + i * 16 + lrow * 4 + r;
                size_t off = (size_t)grow * H + c4 * 4;
                if (EPI == 1) {
                    *reinterpret_cast<f32x4*>(out_fp + off) = o4;
                    *reinterpret_cast<uint2*>(out_bf + off) = pack4(o4);
                } else if (EPI == 2) {
                    f32x4 e4 = *reinterpret_cast<const f32x4*>(out_fp + off);
                    f32x4 ne = {e4[0] + o4[0], e4[1] + o4[1], e4[2] + o4[2], e4[3] + o4[3]};
                    *reinterpret_cast<f32x4*>(out_fp + off) = ne;
                    *reinterpret_cast<uint2*>(out_bf + off) = pack4(ne);
                } else {
                    f32x4 e4 = *reinterpret_cast<const f32x4*>(out_fp + off);
                    f32x4 ne = {e4[0] + o4[0], e4[1] + o4[1], e4[2] + o4[2], e4[3] + o4[3]};
                    *reinterpret_cast<f32x4*>(out_fp + off) = ne;
                    *reinterpret_cast<uint2*>(out_bf + off) = pack4(ne);
                    *reinterpret_cast<uint2*>(enew_bf + off) = pack4(o4);
                }
            }
        }
    }
}

// ---------------- decoder (fp32) ----------------
__global__ void decoder_kernel(const float* __restrict__ x,
                               const float* __restrict__ frames,
                               const float* __restrict__ W1, const float* __restrict__ b1,
                               const float* __restrict__ W2, const float* __restrict__ b2,
                               const float* __restrict__ omean, const float* __restrict__ ostd,
                               float* __restrict__ outp) {
    __shared__ float xr[H];
    __shared__ float hr[H];
    __shared__ float red[2][2];
    int n = blockIdx.x;
    int t = threadIdx.x;  // 128 threads
    xr[t] = x[n * H + t];
    __syncthreads();
    float acc = 0.f;
#pragma unroll 8
    for (int k = 0; k < H; k++) acc += xr[k] * W1[k * H + t];
    hr[t] = fmaxf(acc + b1[t], 0.f);
    __syncthreads();
    float p0 = hr[t] * W2[t * 2 + 0];
    float p1 = hr[t] * W2[t * 2 + 1];
#pragma unroll
    for (int m = 1; m < 64; m <<= 1) {
        p0 += __shfl_xor(p0, m);
        p1 += __shfl_xor(p1, m);
    }
    if ((t & 63) == 0) { red[t >> 6][0] = p0; red[t >> 6][1] = p1; }
    __syncthreads();
    if (t < 2) {
        float d = red[0][t] + red[1][t] + b2[t];
        outp[n * 2 + t] = frames[n * 2 + t] + d * ostd[t] + omean[t];
    }
}

// ---------------- launch ----------------
extern "C" void kernel_launch(void* const* d_in, const int* in_sizes, int n_in,
                              void* d_out, int out_size, void* d_ws, size_t ws_size,
                              hipStream_t stream) {
    (void)in_sizes; (void)n_in; (void)out_size; (void)ws_size;
    const int*   node_type  = (const int*)  d_in[0];
    const int*   edge_index = (const int*)  d_in[1];
    const float* frames     = (const float*)d_in[2];
    const float* edge_feats = (const float*)d_in[3];
    const float* nmean      = (const float*)d_in[4];
    const float* nstd       = (const float*)d_in[5];
    const float* omean      = (const float*)d_in[6];
    const float* ostd       = (const float*)d_in[7];
    const float* enc_nW1    = (const float*)d_in[8];
    const float* enc_nb1    = (const float*)d_in[9];
    const float* enc_nW2    = (const float*)d_in[10];
    const float* enc_nb2    = (const float*)d_in[11];
    const float* enc_nlng   = (const float*)d_in[12];
    const float* enc_nlnb   = (const float*)d_in[13];
    const float* enc_eW1    = (const float*)d_in[14];
    const float* enc_eb1    = (const float*)d_in[15];
    const float* enc_eW2    = (const float*)d_in[16];
    const float* enc_eb2    = (const float*)d_in[17];
    const float* enc_elng   = (const float*)d_in[18];
    const float* enc_elnb   = (const float*)d_in[19];
    const float* eb_W1      = (const float*)d_in[20];
    const float* eb_b1      = (const float*)d_in[21];
    const float* eb_W2      = (const float*)d_in[22];
    const float* eb_b2      = (const float*)d_in[23];
    const float* eb_g       = (const float*)d_in[24];
    const float* eb_bn      = (const float*)d_in[25];
    const float* nb_W1      = (const float*)d_in[26];
    const float* nb_b1      = (const float*)d_in[27];
    const float* nb_W2      = (const float*)d_in[28];
    const float* nb_b2      = (const float*)d_in[29];
    const float* nb_g       = (const float*)d_in[30];
    const float* nb_bn      = (const float*)d_in[31];
    const float* dec_W1     = (const float*)d_in[32];
    const float* dec_b1     = (const float*)d_in[33];
    const float* dec_W2     = (const float*)d_in[34];
    const float* dec_b2     = (const float*)d_in[35];

    const int* snd = edge_index;
    const int* rcv = edge_index + N_EDGES;

    // ---- workspace layout ----
    char* p = (char*)d_ws;
    auto alloc = [&](size_t bytes) {
        void* r = (void*)p;
        p += (bytes + 255) & ~(size_t)255;
        return r;
    };
    float* x_fp  = (float*)alloc((size_t)NPAD * H * 4);
    float* e_fp  = (float*)alloc((size_t)EPAD * H * 4);
    unsigned short* x_bf   = (unsigned short*)alloc((size_t)NPAD * H * 2);
    unsigned short* e_bf   = (unsigned short*)alloc((size_t)EPAD * H * 2);
    unsigned short* enew   = (unsigned short*)alloc((size_t)EPAD * H * 2);
    unsigned short* agg_bf = (unsigned short*)alloc((size_t)NPAD * H * 2);
    unsigned short* a16b   = (unsigned short*)alloc((size_t)NPAD * 32 * 2);
    unsigned short* a4b    = (unsigned short*)alloc((size_t)EPAD * 32 * 2);
    unsigned short* wt_en1 = (unsigned short*)alloc((size_t)128 * 32 * 2);
    unsigned short* wt_ee1 = (unsigned short*)alloc((size_t)128 * 32 * 2);
    unsigned short* wt_en2 = (unsigned short*)alloc((size_t)128 * 128 * 2);
    unsigned short* wt_ee2 = (unsigned short*)alloc((size_t)128 * 128 * 2);
    unsigned short* wt_eb1 = (unsigned short*)alloc((size_t)NLAYERS * 128 * 384 * 2);
    unsigned short* wt_eb2 = (unsigned short*)alloc((size_t)NLAYERS * 128 * 128 * 2);
    unsigned short* wt_nb1 = (unsigned short*)alloc((size_t)NLAYERS * 128 * 256 * 2);
    unsigned short* wt_nb2 = (unsigned short*)alloc((size_t)NLAYERS * 128 * 128 * 2);
    int* counts  = (int*)alloc((size_t)N_NODES * 4);
    int* starts  = (int*)alloc((size_t)N_NODES * 4);
    int* cursor  = (int*)alloc((size_t)N_NODES * 4);
    int* esorted = (int*)alloc((size_t)N_EDGES * 4);
    int* sndP    = (int*)alloc((size_t)N_EDGES * 4);
    int* rcvP    = (int*)alloc((size_t)N_EDGES * 4);

    // ---- CSR + edge presort (receiver-sorted order) ----
    hipMemsetAsync(counts, 0, (size_t)N_NODES * 4, stream);
    hipMemsetAsync(cursor, 0, (size_t)N_NODES * 4, stream);
    hist_kernel<<<(N_EDGES + 255) / 256, 256, 0, stream>>>(rcv, counts);
    scan_kernel<<<1, 1024, 0, stream>>>(counts, starts);
    scatter_kernel<<<(N_EDGES + 255) / 256, 256, 0, stream>>>(rcv, starts, cursor, esorted);
    permute_idx<<<(N_EDGES + 255) / 256, 256, 0, stream>>>(snd, rcv, esorted, sndP, rcvP);

    // ---- prep ----
    prep_node<<<(NPAD * 32 + 255) / 256, 256, 0, stream>>>(node_type, frames, nmean, nstd, a16b);
    prep_edge_sorted<<<(EPAD * 32 + 255) / 256, 256, 0, stream>>>(edge_feats, esorted, a4b);
    auto tw = [&](const float* w, unsigned short* wt, int Kr, int Kp, int nmat) {
        int blocks = nmat * (Kp / 32) * 4;
        transpose_w_frag<<<blocks, 256, 0, stream>>>(w, wt, Kr, Kp, nmat);
    };
    tw(enc_nW1, wt_en1, 11, 32, 1);
    tw(enc_eW1, wt_ee1, 3, 32, 1);
    tw(enc_nW2, wt_en2, 128, 128, 1);
    tw(enc_eW2, wt_ee2, 128, 128, 1);
    tw(eb_W1, wt_eb1, 384, 384, NLAYERS);
    tw(eb_W2, wt_eb2, 128, 128, NLAYERS);
    tw(nb_W1, wt_nb1, 256, 256, NLAYERS);
    tw(nb_W2, wt_nb2, 128, 128, NLAYERS);

    const int gE = EPAD / 128;  // 547 blocks: 4 waves x 32 rows
    const int gN = NPAD / 64;   // 158 blocks: 4 waves x 16 rows
    const unsigned short* nu_ = nullptr;
    const int* ni_ = nullptr;
    unsigned short* nm_ = nullptr;

    // ---- encoders ----
    mlp_pipe<32, 0, 1, 1, 4><<<gN, 256, 0, stream>>>(a16b, nu_, nu_, nu_, ni_, ni_,
        wt_en1, enc_nb1, wt_en2, enc_nb2, enc_nlng, enc_nlnb,
        x_bf, x_fp, nm_, N_NODES);
    mlp_pipe<32, 0, 1, 2, 4><<<gE, 256, 0, stream>>>(a4b, nu_, nu_, nu_, ni_, ni_,
        wt_ee1, enc_eb1, wt_ee2, enc_eb2, enc_elng, enc_elnb,
        e_bf, e_fp, nm_, N_EDGES);

    // ---- processor ----
    for (int l = 0; l < NLAYERS; ++l) {
        mlp_pipe<384, 1, 3, 2, 4><<<gE, 256, 0, stream>>>(nu_, x_bf, e_bf, nu_, sndP, rcvP,
            wt_eb1 + (size_t)l * 128 * 384, eb_b1 + l * H,
            wt_eb2 + (size_t)l * 128 * 128, eb_b2 + l * H, eb_g + l * H, eb_bn + l * H,
            e_bf, e_fp, enew, N_EDGES);
        agg_kernel<<<(N_NODES + 15) / 16, 256, 0, stream>>>(enew, starts, counts, agg_bf);
        mlp_pipe<256, 2, 2, 1, 4><<<gN, 256, 0, stream>>>(nu_, x_bf, nu_, agg_bf, ni_, ni_,
            wt_nb1 + (size_t)l * 128 * 256, nb_b1 + l * H,
            wt_nb2 + (size_t)l * 128 * 128, nb_b2 + l * H, nb_g + l * H, nb_bn + l * H,
            x_bf, x_fp, nm_, N_NODES);
    }

    // ---- decoder (fp32) ----
    decoder_kernel<<<N_NODES, 128, 0, stream>>>(x_fp, frames, dec_W1, dec_b1, dec_W2, dec_b2,
                                                omean, ostd, (float*)d_out);
}

// Round 9
// 1212.092 us; speedup vs baseline: 1.1296x; 1.1296x over previous
//
#include <hip/hip_runtime.h>
#include <hip/hip_bf16.h>

#define N_NODES 10000
#define N_EDGES 70000
#define NPAD 10112   // 158*64
#define EPAD 70016   // 547*128
#define H 128
#define NLAYERS 15
constexpr float LN_EPS = 1e-5f;

typedef __attribute__((ext_vector_type(8))) short short8;
typedef __attribute__((ext_vector_type(4))) float f32x4;

__device__ __forceinline__ float bf2f(unsigned int ulo16) {
    return __uint_as_float(ulo16 << 16);
}
__device__ __forceinline__ unsigned short f2bf(float f) {
    unsigned int x = __float_as_uint(f);
    x += 0x7fffu + ((x >> 16) & 1u);
    return (unsigned short)(x >> 16);
}
__device__ __forceinline__ uint2 pack4(const f32x4& a) {
    uint2 u;
    u.x = (unsigned)f2bf(a[0]) | ((unsigned)f2bf(a[1]) << 16);
    u.y = (unsigned)f2bf(a[2]) | ((unsigned)f2bf(a[3]) << 16);
    return u;
}

// ---------------- prep kernels ----------------
__global__ void prep_node(const int* __restrict__ nt, const float* __restrict__ frames,
                          const float* __restrict__ nm, const float* __restrict__ ns,
                          unsigned short* __restrict__ a16b) {
    int i = blockIdx.x * blockDim.x + threadIdx.x;
    if (i >= NPAD * 32) return;
    int n = i >> 5, k = i & 31;
    float v = 0.f;
    if (n < N_NODES && k < 11) {
        float raw = (k < 2) ? frames[n * 2 + k] : ((nt[n] == (k - 2)) ? 1.f : 0.f);
        v = (raw - nm[k]) / ns[k];
    }
    a16b[i] = f2bf(v);
}

// edge features permuted into CSR (receiver-sorted) order
__global__ void prep_edge_sorted(const float* __restrict__ ef, const int* __restrict__ esorted,
                                 unsigned short* __restrict__ a4b) {
    int i = blockIdx.x * blockDim.x + threadIdx.x;
    if (i >= EPAD * 32) return;
    int p = i >> 5, k = i & 31;
    float v = 0.f;
    if (p < N_EDGES && k < 3) v = ef[(size_t)esorted[p] * 3 + k];
    a4b[i] = f2bf(v);
}

__global__ void permute_idx(const int* __restrict__ snd, const int* __restrict__ rcv,
                            const int* __restrict__ esorted,
                            int* __restrict__ sndP, int* __restrict__ rcvP) {
    int p = blockIdx.x * blockDim.x + threadIdx.x;
    if (p >= N_EDGES) return;
    int j = esorted[p];
    sndP[p] = snd[j];
    rcvP[p] = rcv[j];
}

// W[nmat][Kr][128] fp32 -> fragment-ordered bf16:
// fidx = (((m*(Kp/32) + (k>>5))*8 + (c>>4))*64 + ((k>>3)&3)*16 + (c&15))*8 + (k&7)
__global__ void transpose_w_frag(const float* __restrict__ w, unsigned short* __restrict__ wt,
                                 int Kr, int Kp, int nmat) {
    __shared__ float T[32][33];
    int nkt = Kp / 32;
    int bid = blockIdx.x;
    int m = bid / (nkt * 4);
    int rest = bid % (nkt * 4);
    int kt = rest / 4, ct = rest % 4;
    int t = threadIdx.x;
    int tc = t & 31, tr = t >> 5;  // tr 0..7
#pragma unroll
    for (int rr = 0; rr < 4; ++rr) {
        int k = kt * 32 + tr + rr * 8;
        int c = ct * 32 + tc;
        T[tr + rr * 8][tc] = (k < Kr) ? w[((size_t)m * Kr + k) * H + c] : 0.f;
    }
    __syncthreads();
#pragma unroll
    for (int rr = 0; rr < 4; ++rr) {
        int c = ct * 32 + tr + rr * 8;
        int k = kt * 32 + tc;
        size_t fidx = ((((size_t)m * nkt + (k >> 5)) * 8 + (c >> 4)) * 64
                       + ((k >> 3) & 3) * 16 + (c & 15)) * 8 + (k & 7);
        wt[fidx] = f2bf(T[tc][tr + rr * 8]);
    }
}

// ---------------- CSR build ----------------
__global__ void hist_kernel(const int* __restrict__ rcv, int* __restrict__ counts) {
    int j = blockIdx.x * blockDim.x + threadIdx.x;
    if (j < N_EDGES) atomicAdd(&counts[rcv[j]], 1);
}

__global__ void scan_kernel(const int* __restrict__ counts, int* __restrict__ starts) {
    __shared__ int part[1024];
    const int CH = 10;
    int t = threadIdx.x;
    int base = t * CH;
    int loc[CH];
    int s = 0;
#pragma unroll
    for (int i = 0; i < CH; i++) {
        int idx = base + i;
        int c = (idx < N_NODES) ? counts[idx] : 0;
        loc[i] = s;
        s += c;
    }
    part[t] = s;
    __syncthreads();
    for (int off = 1; off < 1024; off <<= 1) {
        int v = (t >= off) ? part[t - off] : 0;
        __syncthreads();
        part[t] += v;
        __syncthreads();
    }
    int pre = (t > 0) ? part[t - 1] : 0;
#pragma unroll
    for (int i = 0; i < CH; i++) {
        int idx = base + i;
        if (idx < N_NODES) starts[idx] = pre + loc[i];
    }
}

__global__ void scatter_kernel(const int* __restrict__ rcv, const int* __restrict__ starts,
                               int* __restrict__ cursor, int* __restrict__ esorted) {
    int j = blockIdx.x * blockDim.x + threadIdx.x;
    if (j >= N_EDGES) return;
    int r = rcv[j];
    int p = starts[r] + atomicAdd(&cursor[r], 1);
    esorted[p] = j;
}

// ---------------- segmented aggregation (contiguous after presort) ----------------
__global__ void agg_kernel(const unsigned short* __restrict__ enew,
                           const int* __restrict__ starts,
                           const int* __restrict__ counts,
                           unsigned short* __restrict__ aggb) {
    int n = blockIdx.x * 16 + (threadIdx.x >> 4);
    int l = threadIdx.x & 15;  // 8 cols each
    if (n >= N_NODES) return;
    float a[8];
#pragma unroll
    for (int q = 0; q < 8; ++q) a[q] = 0.f;
    int s0 = starts[n], cnt = counts[n];
    const unsigned short* base = enew + (size_t)s0 * H + l * 8;
    for (int j = 0; j < cnt; ++j) {
        uint4 v = *reinterpret_cast<const uint4*>(base + (size_t)j * H);
        a[0] += bf2f(v.x & 0xffffu); a[1] += bf2f(v.x >> 16);
        a[2] += bf2f(v.y & 0xffffu); a[3] += bf2f(v.y >> 16);
        a[4] += bf2f(v.z & 0xffffu); a[5] += bf2f(v.z >> 16);
        a[6] += bf2f(v.w & 0xffffu); a[7] += bf2f(v.w >> 16);
    }
    uint4 o;
    o.x = (unsigned int)f2bf(a[0]) | ((unsigned int)f2bf(a[1]) << 16);
    o.y = (unsigned int)f2bf(a[2]) | ((unsigned int)f2bf(a[3]) << 16);
    o.z = (unsigned int)f2bf(a[4]) | ((unsigned int)f2bf(a[5]) << 16);
    o.w = (unsigned int)f2bf(a[6]) | ((unsigned int)f2bf(a[7]) << 16);
    *reinterpret_cast<uint4*>(aggb + (size_t)n * H + l * 8) = o;
}

// ---------------- 2-phase pipelined fused MLP (block-shared B in LDS) ----------------
// NW waves/block, RW row-tiles/wave (16 rows each). Per 32-k chunk: issue next B
// chunk + next A gather; MFMA current from LDS; ds_write staged B; barrier.
// Stage1 -> relu -> wave-private Hw -> stage2 -> LN epilogue (coalesced via LDS restage).
// AMODE: 0 plain A[rows][K1]; 1 edge concat(x[snd],x[rcv],e); 2 node concat(x,agg)
// EPI: 1 bias+LN -> out_fp, out_bf
//      2 bias+LN -> out_fp += o; out_bf = bf16(new)           (node residual)
//      3 bias+LN -> out_fp += o; out_bf = bf16(new); enew = bf16(o)
template <int K1, int AMODE, int EPI, int RW, int NW>
__launch_bounds__(NW * 64)
__global__ void mlp_pipe(const unsigned short* __restrict__ A,
                         const unsigned short* __restrict__ Xb,
                         const unsigned short* __restrict__ Eb,
                         const unsigned short* __restrict__ Gb,
                         const int* __restrict__ snd,
                         const int* __restrict__ rcv,
                         const unsigned short* __restrict__ Bt1,
                         const float* __restrict__ bias1,
                         const unsigned short* __restrict__ Bt2,
                         const float* __restrict__ bias2,
                         const float* __restrict__ lng,
                         const float* __restrict__ lnb,
                         unsigned short* __restrict__ out_bf,
                         float* __restrict__ out_fp,
                         unsigned short* __restrict__ enew_bf,
                         int nrows) {
    constexpr int NC1 = K1 / 32;
    constexpr int NC2 = 4;
    constexpr int NT = NC1 + NC2;
    constexpr int TH = NW * 64;
    constexpr int SLOADS = 8192 / (TH * 16);   // uint4 loads/thread per 8KB chunk
    constexpr int SH = H + 8;

    __shared__ __attribute__((aligned(16))) unsigned short Bs[2][4096];
    __shared__ __attribute__((aligned(16))) unsigned short Hs[NW * 16 * RW * SH];

    const int tid = threadIdx.x;
    const int wave = tid >> 6;
    const int lane = tid & 63;
    const int l15 = lane & 15;
    const int lhi = lane >> 4;
    const int wrow0 = (blockIdx.x * NW + wave) * (16 * RW);
    unsigned short* Hw = Hs + wave * (16 * RW) * SH;

    // per-lane A-source row pointers (A-frag row = wrow0 + i*16 + l15)
    const unsigned short* pS[RW];
    const unsigned short* pR[RW];
    const unsigned short* pE[RW];
#pragma unroll
    for (int i = 0; i < RW; ++i) {
        int grow = wrow0 + i * 16 + l15;
        if (AMODE == 0) {
            pS[i] = A + (size_t)grow * K1;
        } else if (AMODE == 1) {
            int e = (grow < nrows) ? grow : (nrows - 1);
            pS[i] = Xb + (size_t)snd[e] * H;
            pR[i] = Xb + (size_t)rcv[e] * H;
            pE[i] = Eb + (size_t)grow * H;
        } else {
            pS[i] = Xb + (size_t)grow * H;
            pR[i] = Gb + (size_t)grow * H;
        }
    }

    auto gatherA = [&](int t, short8* dst) {
#pragma unroll
        for (int i = 0; i < RW; ++i) {
            int kc = t * 32;
            const unsigned short* s;
            if (AMODE == 0)      s = pS[i] + kc;
            else if (AMODE == 1) s = (kc < H) ? pS[i] + kc
                                 : (kc < 2 * H) ? pR[i] + (kc - H)
                                 : pE[i] + (kc - 2 * H);
            else                 s = (kc < H) ? pS[i] + kc : pR[i] + (kc - H);
            dst[i] = *reinterpret_cast<const short8*>(s + lhi * 8);
        }
    };
    auto bsrc = [&](int t) -> const unsigned short* {
        return (t < NC1) ? Bt1 + (size_t)t * 4096 : Bt2 + (size_t)(t - NC1) * 4096;
    };

    // bias1 early (held in regs)
    float b1v[8];
#pragma unroll
    for (int j = 0; j < 8; ++j) b1v[j] = bias1[j * 16 + l15];

    // ---- prologue: stage chunk 0, gather A chunk 0 ----
    {
        const unsigned short* src = bsrc(0);
        uint4 st[SLOADS];
#pragma unroll
        for (int s2 = 0; s2 < SLOADS; ++s2)
            st[s2] = *reinterpret_cast<const uint4*>(src + (size_t)(s2 * TH + tid) * 8);
#pragma unroll
        for (int s2 = 0; s2 < SLOADS; ++s2)
            *reinterpret_cast<uint4*>(&Bs[0][(s2 * TH + tid) * 8]) = st[s2];
    }
    short8 af[RW];
    gatherA(0, af);
    __syncthreads();

    f32x4 acc[RW][8];
#pragma unroll
    for (int i = 0; i < RW; i++)
#pragma unroll
        for (int j = 0; j < 8; j++) acc[i][j] = (f32x4){0.f, 0.f, 0.f, 0.f};

    // ---- main pipelined loop over NT chunks ----
#pragma unroll
    for (int t = 0; t < NT; ++t) {
        const int cur = t & 1;
        // (a) issue next-chunk B loads + next A gather (latency hides under (b))
        uint4 stn[SLOADS];
        if (t + 1 < NT) {
            const unsigned short* src = bsrc(t + 1);
#pragma unroll
            for (int s2 = 0; s2 < SLOADS; ++s2)
                stn[s2] = *reinterpret_cast<const uint4*>(src + (size_t)(s2 * TH + tid) * 8);
        }
        short8 afn[RW];
        if (t + 1 < NC1) gatherA(t + 1, afn);

        // (b) compute chunk t
        short8 av[RW];
        if (t < NC1) {
#pragma unroll
            for (int i = 0; i < RW; ++i) av[i] = af[i];
        } else {
            const int c2 = t - NC1;
#pragma unroll
            for (int i = 0; i < RW; ++i)
                av[i] = *reinterpret_cast<const short8*>(
                    &Hw[(i * 16 + l15) * SH + c2 * 32 + lhi * 8]);
        }
#pragma unroll
        for (int j = 0; j < 8; ++j) {
            short8 bfr = *reinterpret_cast<const short8*>(&Bs[cur][j * 512 + lane * 8]);
#pragma unroll
            for (int i = 0; i < RW; ++i)
                acc[i][j] = __builtin_amdgcn_mfma_f32_16x16x32_bf16(av[i], bfr, acc[i][j], 0, 0, 0);
        }

        // (c) stage transition: h = relu(acc+b1) -> wave-private Hw; reset acc
        if (t == NC1 - 1) {
#pragma unroll
            for (int i = 0; i < RW; ++i)
#pragma unroll
                for (int r = 0; r < 4; ++r) {
                    int rl = i * 16 + lhi * 4 + r;
#pragma unroll
                    for (int j = 0; j < 8; ++j) {
                        float v = acc[i][j][r] + b1v[j];
                        Hw[rl * SH + j * 16 + l15] = f2bf(v > 0.f ? v : 0.f);
                    }
                }
#pragma unroll
            for (int i = 0; i < RW; ++i)
#pragma unroll
                for (int j = 0; j < 8; ++j) acc[i][j] = (f32x4){0.f, 0.f, 0.f, 0.f};
        }

        // (d) write staged B to other buffer; advance
        if (t + 1 < NT) {
#pragma unroll
            for (int s2 = 0; s2 < SLOADS; ++s2)
                *reinterpret_cast<uint4*>(&Bs[cur ^ 1][(s2 * TH + tid) * 8]) = stn[s2];
            if (t + 1 < NC1) {
#pragma unroll
                for (int i = 0; i < RW; ++i) af[i] = afn[i];
            }
            __syncthreads();
        }
    }

    // ---- epilogue: bias2 + LN; coalesced stores via wave-private LDS restage ----
    float bv[8], gv[8], lv[8];
#pragma unroll
    for (int j = 0; j < 8; ++j) {
        bv[j] = bias2[j * 16 + l15];
        gv[j] = lng[j * 16 + l15];
        lv[j] = lnb[j * 16 + l15];
    }

    // Hw strip is dead after the last stage-2 ds_read (same-wave program order).
    // Reuse as [4][132] fp32 scratch (2112 B <= 4352 B strip).
    float* Epf = reinterpret_cast<float*>(Hw);

#pragma unroll
    for (int i = 0; i < RW; ++i) {
#pragma unroll
        for (int r = 0; r < 4; ++r) {
            float v[8];
            float s = 0.f, s2 = 0.f;
#pragma unroll
            for (int j = 0; j < 8; ++j) {
                v[j] = acc[i][j][r] + bv[j];
                s += v[j];
                s2 += v[j] * v[j];
            }
#pragma unroll
            for (int m = 1; m < 16; m <<= 1) {
                s += __shfl_xor(s, m);
                s2 += __shfl_xor(s2, m);
            }
            float mean = s * (1.f / 128.f);
            float var = s2 * (1.f / 128.f) - mean * mean;
            float rstd = rsqrtf(var + LN_EPS);
#pragma unroll
            for (int j = 0; j < 8; ++j)
                Epf[lhi * 132 + j * 16 + l15] = (v[j] - mean) * rstd * gv[j] + lv[j];
#pragma unroll
            for (int q = 0; q < 2; ++q) {
                int lin = q * 64 + lane;
                int lrow = lin >> 5;     // 0..3
                int c4 = lin & 31;       // float4 column index
                f32x4 o4 = *reinterpret_cast<const f32x4*>(&Epf[lrow * 132 + c4 * 4]);
                int grow = wrow0 + i * 16 + lrow * 4 + r;
                size_t off = (size_t)grow * H + c4 * 4;
                if (EPI == 1) {
                    *reinterpret_cast<f32x4*>(out_fp + off) = o4;
                    *reinterpret_cast<uint2*>(out_bf + off) = pack4(o4);
                } else if (EPI == 2) {
                    f32x4 e4 = *reinterpret_cast<const f32x4*>(out_fp + off);
                    f32x4 ne = {e4[0] + o4[0], e4[1] + o4[1], e4[2] + o4[2], e4[3] + o4[3]};
                    *reinterpret_cast<f32x4*>(out_fp + off) = ne;
                    *reinterpret_cast<uint2*>(out_bf + off) = pack4(ne);
                } else {
                    f32x4 e4 = *reinterpret_cast<const f32x4*>(out_fp + off);
                    f32x4 ne = {e4[0] + o4[0], e4[1] + o4[1], e4[2] + o4[2], e4[3] + o4[3]};
                    *reinterpret_cast<f32x4*>(out_fp + off) = ne;
                    *reinterpret_cast<uint2*>(out_bf + off) = pack4(ne);
                    *reinterpret_cast<uint2*>(enew_bf + off) = pack4(o4);
                }
            }
        }
    }
}

// ---------------- decoder (fp32) ----------------
__global__ void decoder_kernel(const float* __restrict__ x,
                               const float* __restrict__ frames,
                               const float* __restrict__ W1, const float* __restrict__ b1,
                               const float* __restrict__ W2, const float* __restrict__ b2,
                               const float* __restrict__ omean, const float* __restrict__ ostd,
                               float* __restrict__ outp) {
    __shared__ float xr[H];
    __shared__ float hr[H];
    __shared__ float red[2][2];
    int n = blockIdx.x;
    int t = threadIdx.x;  // 128 threads
    xr[t] = x[n * H + t];
    __syncthreads();
    float acc = 0.f;
#pragma unroll 8
    for (int k = 0; k < H; k++) acc += xr[k] * W1[k * H + t];
    hr[t] = fmaxf(acc + b1[t], 0.f);
    __syncthreads();
    float p0 = hr[t] * W2[t * 2 + 0];
    float p1 = hr[t] * W2[t * 2 + 1];
#pragma unroll
    for (int m = 1; m < 64; m <<= 1) {
        p0 += __shfl_xor(p0, m);
        p1 += __shfl_xor(p1, m);
    }
    if ((t & 63) == 0) { red[t >> 6][0] = p0; red[t >> 6][1] = p1; }
    __syncthreads();
    if (t < 2) {
        float d = red[0][t] + red[1][t] + b2[t];
        outp[n * 2 + t] = frames[n * 2 + t] + d * ostd[t] + omean[t];
    }
}

// ---------------- launch ----------------
extern "C" void kernel_launch(void* const* d_in, const int* in_sizes, int n_in,
                              void* d_out, int out_size, void* d_ws, size_t ws_size,
                              hipStream_t stream) {
    (void)in_sizes; (void)n_in; (void)out_size; (void)ws_size;
    const int*   node_type  = (const int*)  d_in[0];
    const int*   edge_index = (const int*)  d_in[1];
    const float* frames     = (const float*)d_in[2];
    const float* edge_feats = (const float*)d_in[3];
    const float* nmean      = (const float*)d_in[4];
    const float* nstd       = (const float*)d_in[5];
    const float* omean      = (const float*)d_in[6];
    const float* ostd       = (const float*)d_in[7];
    const float* enc_nW1    = (const float*)d_in[8];
    const float* enc_nb1    = (const float*)d_in[9];
    const float* enc_nW2    = (const float*)d_in[10];
    const float* enc_nb2    = (const float*)d_in[11];
    const float* enc_nlng   = (const float*)d_in[12];
    const float* enc_nlnb   = (const float*)d_in[13];
    const float* enc_eW1    = (const float*)d_in[14];
    const float* enc_eb1    = (const float*)d_in[15];
    const float* enc_eW2    = (const float*)d_in[16];
    const float* enc_eb2    = (const float*)d_in[17];
    const float* enc_elng   = (const float*)d_in[18];
    const float* enc_elnb   = (const float*)d_in[19];
    const float* eb_W1      = (const float*)d_in[20];
    const float* eb_b1      = (const float*)d_in[21];
    const float* eb_W2      = (const float*)d_in[22];
    const float* eb_b2      = (const float*)d_in[23];
    const float* eb_g       = (const float*)d_in[24];
    const float* eb_bn      = (const float*)d_in[25];
    const float* nb_W1      = (const float*)d_in[26];
    const float* nb_b1      = (const float*)d_in[27];
    const float* nb_W2      = (const float*)d_in[28];
    const float* nb_b2      = (const float*)d_in[29];
    const float* nb_g       = (const float*)d_in[30];
    const float* nb_bn      = (const float*)d_in[31];
    const float* dec_W1     = (const float*)d_in[32];
    const float* dec_b1     = (const float*)d_in[33];
    const float* dec_W2     = (const float*)d_in[34];
    const float* dec_b2     = (const float*)d_in[35];

    const int* snd = edge_index;
    const int* rcv = edge_index + N_EDGES;

    // ---- workspace layout ----
    char* p = (char*)d_ws;
    auto alloc = [&](size_t bytes) {
        void* r = (void*)p;
        p += (bytes + 255) & ~(size_t)255;
        return r;
    };
    float* x_fp  = (float*)alloc((size_t)NPAD * H * 4);
    float* e_fp  = (float*)alloc((size_t)EPAD * H * 4);
    unsigned short* x_bf   = (unsigned short*)alloc((size_t)NPAD * H * 2);
    unsigned short* e_bf   = (unsigned short*)alloc((size_t)EPAD * H * 2);
    unsigned short* enew   = (unsigned short*)alloc((size_t)EPAD * H * 2);
    unsigned short* agg_bf = (unsigned short*)alloc((size_t)NPAD * H * 2);
    unsigned short* a16b   = (unsigned short*)alloc((size_t)NPAD * 32 * 2);
    unsigned short* a4b    = (unsigned short*)alloc((size_t)EPAD * 32 * 2);
    unsigned short* wt_en1 = (unsigned short*)alloc((size_t)128 * 32 * 2);
    unsigned short* wt_ee1 = (unsigned short*)alloc((size_t)128 * 32 * 2);
    unsigned short* wt_en2 = (unsigned short*)alloc((size_t)128 * 128 * 2);
    unsigned short* wt_ee2 = (unsigned short*)alloc((size_t)128 * 128 * 2);
    unsigned short* wt_eb1 = (unsigned short*)alloc((size_t)NLAYERS * 128 * 384 * 2);
    unsigned short* wt_eb2 = (unsigned short*)alloc((size_t)NLAYERS * 128 * 128 * 2);
    unsigned short* wt_nb1 = (unsigned short*)alloc((size_t)NLAYERS * 128 * 256 * 2);
    unsigned short* wt_nb2 = (unsigned short*)alloc((size_t)NLAYERS * 128 * 128 * 2);
    int* counts  = (int*)alloc((size_t)N_NODES * 4);
    int* starts  = (int*)alloc((size_t)N_NODES * 4);
    int* cursor  = (int*)alloc((size_t)N_NODES * 4);
    int* esorted = (int*)alloc((size_t)N_EDGES * 4);
    int* sndP    = (int*)alloc((size_t)N_EDGES * 4);
    int* rcvP    = (int*)alloc((size_t)N_EDGES * 4);

    // ---- CSR + edge presort (receiver-sorted order) ----
    hipMemsetAsync(counts, 0, (size_t)N_NODES * 4, stream);
    hipMemsetAsync(cursor, 0, (size_t)N_NODES * 4, stream);
    hist_kernel<<<(N_EDGES + 255) / 256, 256, 0, stream>>>(rcv, counts);
    scan_kernel<<<1, 1024, 0, stream>>>(counts, starts);
    scatter_kernel<<<(N_EDGES + 255) / 256, 256, 0, stream>>>(rcv, starts, cursor, esorted);
    permute_idx<<<(N_EDGES + 255) / 256, 256, 0, stream>>>(snd, rcv, esorted, sndP, rcvP);

    // ---- prep ----
    prep_node<<<(NPAD * 32 + 255) / 256, 256, 0, stream>>>(node_type, frames, nmean, nstd, a16b);
    prep_edge_sorted<<<(EPAD * 32 + 255) / 256, 256, 0, stream>>>(edge_feats, esorted, a4b);
    auto tw = [&](const float* w, unsigned short* wt, int Kr, int Kp, int nmat) {
        int blocks = nmat * (Kp / 32) * 4;
        transpose_w_frag<<<blocks, 256, 0, stream>>>(w, wt, Kr, Kp, nmat);
    };
    tw(enc_nW1, wt_en1, 11, 32, 1);
    tw(enc_eW1, wt_ee1, 3, 32, 1);
    tw(enc_nW2, wt_en2, 128, 128, 1);
    tw(enc_eW2, wt_ee2, 128, 128, 1);
    tw(eb_W1, wt_eb1, 384, 384, NLAYERS);
    tw(eb_W2, wt_eb2, 128, 128, NLAYERS);
    tw(nb_W1, wt_nb1, 256, 256, NLAYERS);
    tw(nb_W2, wt_nb2, 128, 128, NLAYERS);

    const int gE = EPAD / 128;  // 547 blocks: 8 waves x 16 rows
    const int gN = NPAD / 64;   // 158 blocks: 4 waves x 16 rows
    const unsigned short* nu_ = nullptr;
    const int* ni_ = nullptr;
    unsigned short* nm_ = nullptr;

    // ---- encoders ----
    mlp_pipe<32, 0, 1, 1, 4><<<gN, 256, 0, stream>>>(a16b, nu_, nu_, nu_, ni_, ni_,
        wt_en1, enc_nb1, wt_en2, enc_nb2, enc_nlng, enc_nlnb,
        x_bf, x_fp, nm_, N_NODES);
    mlp_pipe<32, 0, 1, 1, 8><<<gE, 512, 0, stream>>>(a4b, nu_, nu_, nu_, ni_, ni_,
        wt_ee1, enc_eb1, wt_ee2, enc_eb2, enc_elng, enc_elnb,
        e_bf, e_fp, nm_, N_EDGES);

    // ---- processor ----
    for (int l = 0; l < NLAYERS; ++l) {
        mlp_pipe<384, 1, 3, 1, 8><<<gE, 512, 0, stream>>>(nu_, x_bf, e_bf, nu_, sndP, rcvP,
            wt_eb1 + (size_t)l * 128 * 384, eb_b1 + l * H,
            wt_eb2 + (size_t)l * 128 * 128, eb_b2 + l * H, eb_g + l * H, eb_bn + l * H,
            e_bf, e_fp, enew, N_EDGES);
        agg_kernel<<<(N_NODES + 15) / 16, 256, 0, stream>>>(enew, starts, counts, agg_bf);
        mlp_pipe<256, 2, 2, 1, 4><<<gN, 256, 0, stream>>>(nu_, x_bf, nu_, agg_bf, ni_, ni_,
            wt_nb1 + (size_t)l * 128 * 256, nb_b1 + l * H,
            wt_nb2 + (size_t)l * 128 * 128, nb_b2 + l * H, nb_g + l * H, nb_bn + l * H,
            x_bf, x_fp, nm_, N_NODES);
    }

    // ---- decoder (fp32) ----
    decoder_kernel<<<N_NODES, 128, 0, stream>>>(x_fp, frames, dec_W1, dec_b1, dec_W2, dec_b2,
                                                omean, ostd, (float*)d_out);
}